// Round 7
// baseline (114.006 us; speedup 1.0000x reference)
//
#include <hip/hip_runtime.h>

#define HH 64
#define WW 64
#define NN 4096
#define DZc 128
#define KS 8
#define BK 32
#define NKT (NN / KS / BK)        // 16 k-tiles per block
#define CELLS 2097152             // 4*64*64*128 output floats
#define WS_NEED (8ull * CELLS * 2ull)   // f16 partials: 32 MB

typedef __fp16 v2fp16 __attribute__((ext_vector_type(2)));
typedef _Float16 v4h __attribute__((ext_vector_type(4)));
typedef _Float16 v8h __attribute__((ext_vector_type(8)));
typedef float v16f __attribute__((ext_vector_type(16)));

__device__ __forceinline__ unsigned pk16(float lo, float hi){
  union { v2fp16 h; unsigned u; } c;
  c.h = __builtin_amdgcn_cvt_pkrtz(lo, hi);
  return c.u;
}
__device__ __forceinline__ float fexp2(float x){ return __builtin_amdgcn_exp2f(x); }

__global__ void init_out_kernel(const float4* __restrict__ zc_on,
                                const int* __restrict__ ignore,
                                float4* __restrict__ out){
  int i = blockIdx.x * blockDim.x + threadIdx.x;
  float4 v = zc_on[i];
  if (ignore[0]) { v.x = 0.f; v.y = 0.f; v.z = 0.f; v.w = 0.f; }
  out[i] = v;
}

// sum 8 f16 K-split partials + zc_on -> out
__global__ void reduce_kernel(const v4h* __restrict__ part,
                              const float4* __restrict__ zc_on,
                              const int* __restrict__ ignore,
                              float4* __restrict__ out){
  int i = blockIdx.x * blockDim.x + threadIdx.x;
  float4 s = zc_on[i];
  if (ignore[0]) { s.x = 0.f; s.y = 0.f; s.z = 0.f; s.w = 0.f; }
  #pragma unroll
  for (int ks = 0; ks < KS; ++ks){
    v4h p = part[(size_t)ks * (CELLS / 4) + i];
    s.x += (float)p[0]; s.y += (float)p[1]; s.z += (float)p[2]; s.w += (float)p[3];
  }
  out[i] = s;
}

// Occupancy-first retile (r6 post-mortem: acc AGPRs + VGPRs ~248/wave capped
// us at 2 waves/SIMD; LDS 46KB capped 2 blocks/CU).
// Grid: 1024 blocks = ks(8, HIGH) x b(4) x mt(32) -> 4 blocks/CU resident.
// Block: 256 thr = 4 waves; BM=128 (16iy x 8ix), BD=128, BK=32, 16 k-tiles.
// Wave: 64m x 64d = 2x2 tiles of 32x32x16 f16 MFMA -> acc 64 regs, total <=128
//   => 4 waves/SIMD, 16 waves/CU (2x r6). LDS 22KB/block.
__global__ __launch_bounds__(256, 4)
void setconv_gemm_kernel(const float* __restrict__ xc_off,
                         const float* __restrict__ xc_on,
                         const float* __restrict__ zc_off,
                         const float* __restrict__ lsp,
                         _Float16* __restrict__ part,
                         float* __restrict__ out)
{
  __shared__ unsigned short zt[2][128][34];  // Z^T f16 [d][k], stride 17 dw (odd => conflict-free)
  __shared__ unsigned short gt[2][24][48];   // f16 g-tables rows 0-15 gy, 16-23 gx; stride 96B (16B-aligned, <=2-way)

  const int tid = threadIdx.x;
  const int bid = blockIdx.x;
  const int ks  = bid >> 7;          // HIGH bits -> same-XCD partial groups
  const int rem = bid & 127;
  const int b   = rem >> 5;
  const int mt  = rem & 31;
  const int iy0 = (mt >> 3) * 16;
  const int ix0 = (mt & 7) * 8;
  const int nbase = ks * (NN / KS);

  const float lsy = 1e-5f + log1pf(expf(lsp[0]));
  const float lsx = 1e-5f + log1pf(expf(lsp[1]));
  const float LOG2E = 1.44269504088896340736f;
  const float ay = -0.5f * LOG2E / (lsy * lsy);
  const float ax = -0.5f * LOG2E / (lsx * lsx);

  // ---- gtab staging: 24 rows x 16 k-pairs; thread t -> gy row t>>4, pair t&15;
  //      threads <128 also gx row 16+(t>>4)
  const int gp = tid & 15;           // k-pair: k = 2*gp, 2*gp+1
  const int grow = tid >> 4;         // gy row 0..15
  const float gcy = xc_on[((b * HH + iy0 + grow) * WW) * 2];
  const bool hasx = (tid < 128);
  const float gcx = hasx ? xc_on[(b * HH * WW + ix0 + grow) * 2 + 1] : 0.f;

  // ---- Z staging: thread -> d = tid&127, n-half nh = tid>>7 (16 n each)
  const int zd = tid & 127;
  const int nh = tid >> 7;

  // ---- consumer mapping
  const int lane = tid & 63;
  const int wv  = tid >> 6;
  const int wm  = wv >> 1;           // m-half (64 m)
  const int wdh = wv & 1;            // d-half (64 d)
  const int l31 = lane & 31;
  const int lh  = lane >> 5;
  const int gxr = 16 + (l31 & 7);
  const int gyr = wm * 8 + (l31 >> 3);   // + mtl*4

  v16f acc[2][2];
  #pragma unroll
  for (int m = 0; m < 2; ++m)
    #pragma unroll
    for (int d = 0; d < 2; ++d)
      #pragma unroll
      for (int r = 0; r < 16; ++r)
        acc[m][d][r] = 0.f;

  const float* xb = xc_off + (size_t)b * NN * 2;
  const float* zb = zc_off + (size_t)b * NN * DZc;

  // ---- prologue: stage k-tile 0 into buf 0
  {
    const int n0 = nbase;
    float4 xq = *(const float4*)&xb[(size_t)(n0 + 2 * gp) * 2];  // (y0,x0,y1,x1)
    float dy0 = gcy - xq.x, dy1 = gcy - xq.z;
    ((unsigned*)&gt[0][0][0])[grow * 24 + gp] = pk16(fexp2(ay * dy0 * dy0), fexp2(ay * dy1 * dy1));
    if (hasx){
      float dx0 = gcx - xq.y, dx1 = gcx - xq.w;
      ((unsigned*)&gt[0][0][0])[(16 + grow) * 24 + gp] = pk16(fexp2(ax * dx0 * dx0), fexp2(ax * dx1 * dx1));
    }
    float zv[16];
    #pragma unroll
    for (int i = 0; i < 16; ++i)
      zv[i] = zb[(size_t)(n0 + nh * 16 + i) * DZc + zd];
    #pragma unroll
    for (int j = 0; j < 4; ++j){
      union { unsigned u[2]; double d; } w;
      w.u[0] = pk16(zv[4 * j],     zv[4 * j + 1]);
      w.u[1] = pk16(zv[4 * j + 2], zv[4 * j + 3]);
      *(double*)&zt[0][zd][nh * 16 + 4 * j] = w.d;
    }
  }
  __syncthreads();

  #pragma unroll 1
  for (int kt = 0; kt < NKT; ++kt){
    const int buf  = kt & 1;
    const int nbuf = buf ^ 1;
    const bool have_next = (kt + 1 < NKT);
    const int n1 = nbase + (kt + 1) * BK;

    // ---- issue next tile's global loads
    float zv[16];
    float4 xq_n = (float4){0.f, 0.f, 0.f, 0.f};
    if (have_next){
      #pragma unroll
      for (int i = 0; i < 16; ++i)
        zv[i] = zb[(size_t)(n1 + nh * 16 + i) * DZc + zd];
      xq_n = *(const float4*)&xb[(size_t)(n1 + 2 * gp) * 2];
    }

    // ---- consume 2 ksteps (K=16 each)
    #pragma unroll
    for (int kstep = 0; kstep < 2; ++kstep){
      const int k0 = kstep * 16 + lh * 8;
      const v8h xu = *(const v8h*)&gt[buf][gxr][k0];
      v8h bfr[2];
      #pragma unroll
      for (int dtl = 0; dtl < 2; ++dtl){
        union { v4h h[2]; v8h v; } zu;
        zu.h[0] = *(const v4h*)&zt[buf][wdh * 64 + dtl * 32 + l31][k0];
        zu.h[1] = *(const v4h*)&zt[buf][wdh * 64 + dtl * 32 + l31][k0 + 4];
        bfr[dtl] = zu.v;
      }
      #pragma unroll
      for (int mtl = 0; mtl < 2; ++mtl){
        const v8h yu = *(const v8h*)&gt[buf][gyr + mtl * 4][k0];
        v8h av = yu * xu;
        #pragma unroll
        for (int dtl = 0; dtl < 2; ++dtl)
          acc[mtl][dtl] = __builtin_amdgcn_mfma_f32_32x32x16_f16(av, bfr[dtl], acc[mtl][dtl], 0, 0, 0);
      }
    }

    // ---- pack & write next tile
    if (have_next){
      #pragma unroll
      for (int j = 0; j < 4; ++j){
        union { unsigned u[2]; double d; } w;
        w.u[0] = pk16(zv[4 * j],     zv[4 * j + 1]);
        w.u[1] = pk16(zv[4 * j + 2], zv[4 * j + 3]);
        *(double*)&zt[nbuf][zd][nh * 16 + 4 * j] = w.d;
      }
      float dy0 = gcy - xq_n.x, dy1 = gcy - xq_n.z;
      ((unsigned*)&gt[nbuf][0][0])[grow * 24 + gp] = pk16(fexp2(ay * dy0 * dy0), fexp2(ay * dy1 * dy1));
      if (hasx){
        float dx0 = gcx - xq_n.y, dx1 = gcx - xq_n.w;
        ((unsigned*)&gt[nbuf][0][0])[(16 + grow) * 24 + gp] = pk16(fexp2(ax * dx0 * dx0), fexp2(ax * dx1 * dx1));
      }
    }
    __syncthreads();
  }

  // ---- epilogue
  // C/D of 32x32: col = lane&31 (d), row = (reg&3) + 8*(reg>>2) + 4*(lane>>5)
  if (part){
    _Float16* pw = part + (size_t)ks * CELLS;
    #pragma unroll
    for (int mtl = 0; mtl < 2; ++mtl)
      #pragma unroll
      for (int dtl = 0; dtl < 2; ++dtl){
        const int d = wdh * 64 + dtl * 32 + l31;
        #pragma unroll
        for (int reg = 0; reg < 16; ++reg){
          const int row = (reg & 3) + 8 * (reg >> 2) + 4 * lh;
          const int m = wm * 64 + mtl * 32 + row;
          const int iy = iy0 + (m >> 3);
          const int ix = ix0 + (m & 7);
          pw[((b * HH + iy) * WW + ix) * DZc + d] = (_Float16)acc[mtl][dtl][reg];
        }
      }
  } else {
    #pragma unroll
    for (int mtl = 0; mtl < 2; ++mtl)
      #pragma unroll
      for (int dtl = 0; dtl < 2; ++dtl){
        const int d = wdh * 64 + dtl * 32 + l31;
        #pragma unroll
        for (int reg = 0; reg < 16; ++reg){
          const int row = (reg & 3) + 8 * (reg >> 2) + 4 * lh;
          const int m = wm * 64 + mtl * 32 + row;
          const int iy = iy0 + (m >> 3);
          const int ix = ix0 + (m & 7);
          unsafeAtomicAdd(&out[((b * HH + iy) * WW + ix) * DZc + d], acc[mtl][dtl][reg]);
        }
      }
  }
}

extern "C" void kernel_launch(void* const* d_in, const int* in_sizes, int n_in,
                              void* d_out, int out_size, void* d_ws, size_t ws_size,
                              hipStream_t stream){
  const float* xc_off = (const float*)d_in[0];
  const float* xc_on  = (const float*)d_in[1];
  const float* zc_off = (const float*)d_in[2];
  const float* zc_on  = (const float*)d_in[3];
  const float* lsp    = (const float*)d_in[4];
  const int*   ign    = (const int*)d_in[5];
  float* out = (float*)d_out;

  if (ws_size >= WS_NEED){
    _Float16* part = (_Float16*)d_ws;
    setconv_gemm_kernel<<<KS * 128, 256, 0, stream>>>(xc_off, xc_on, zc_off, lsp, part, out);
    reduce_kernel<<<CELLS / 4 / 256, 256, 0, stream>>>((const v4h*)part, (const float4*)zc_on, ign, (float4*)out);
  } else {
    init_out_kernel<<<out_size / 1024, 256, 0, stream>>>((const float4*)zc_on, ign, (float4*)out);
    setconv_gemm_kernel<<<KS * 128, 256, 0, stream>>>(xc_off, xc_on, zc_off, lsp, nullptr, out);
  }
}